// Round 9
// baseline (233.433 us; speedup 1.0000x reference)
//
#include <hip/hip_runtime.h>
#include <hip/hip_bf16.h>
#include <hip/hip_fp16.h>
#include <math.h>

#define NDOC 4
#define CCC  1024
#define DDD  768
#define HHH  12
#define EEE  42
#define MMM  8
#define PPP  1024
#define NBQ  12
#define NK   99
#define NPAD 112
#define NSLICE 48

typedef __attribute__((ext_vector_type(8))) short short8v;
typedef __attribute__((ext_vector_type(8))) _Float16 half8;
typedef __attribute__((ext_vector_type(4))) float floatx4;

__device__ __forceinline__ unsigned short f32_to_bf16u(float f) {
  return __builtin_bit_cast(unsigned short, __float2bfloat16(f));
}
__device__ __forceinline__ unsigned short f32_to_f16u(float f) {
  return __builtin_bit_cast(unsigned short, __float2half(f));
}

// ---------------- K1: e_emb = logsumexp over valid mentions (bf16 out) -----
__global__ __launch_bounds__(256) void k_eemb(const float* __restrict__ seq,
    const int* __restrict__ pos, const int* __restrict__ mask,
    unsigned short* __restrict__ eembB) {
  int e = blockIdx.x, doc = blockIdx.y;
  int base = (doc*EEE + e)*MMM;
  int p[MMM], mk[MMM];
#pragma unroll
  for (int m = 0; m < MMM; ++m) { p[m] = pos[base+m] + 1; mk[m] = mask[base+m]; }
  for (int d0 = threadIdx.x; d0 < DDD; d0 += 256) {
    float v[MMM]; float mx = -INFINITY;
#pragma unroll
    for (int m = 0; m < MMM; ++m) {
      v[m] = seq[(doc*CCC + p[m])*DDD + d0];
      if (mk[m]) mx = fmaxf(mx, v[m]);
    }
    float s = 0.f;
#pragma unroll
    for (int m = 0; m < MMM; ++m) if (mk[m]) s += expf(v[m]-mx);
    eembB[(doc*EEE + e)*DDD + d0] = f32_to_bf16u(logf(s) + mx);
  }
}

// ---------------- K2: e_att (fp32) ----------------------------------------
__global__ __launch_bounds__(256) void k_eatt(const float* __restrict__ att,
    const int* __restrict__ pos, const int* __restrict__ mask,
    float* __restrict__ eatt) {
  int head = blockIdx.x, e = blockIdx.y, doc = blockIdx.z;
  int base = (doc*EEE + e)*MMM;
  int j = threadIdx.x * 4;
  float ax=0.f, ay=0.f, az=0.f, aw=0.f; float cnt = 0.f;
#pragma unroll
  for (int m = 0; m < MMM; ++m) {
    int mk = mask[base+m];
    cnt += (float)mk;
    if (mk) {
      int pp = pos[base+m] + 1;
      const float4 a = *(const float4*)&att[((size_t)(doc*HHH + head)*CCC + pp)*CCC + j];
      ax += a.x; ay += a.y; az += a.z; aw += a.w;
    }
  }
  float inv = 1.f / cnt;
  float4 o; o.x = ax*inv; o.y = ay*inv; o.z = az*inv; o.w = aw*inv;
  *(float4*)&eatt[((size_t)((doc*EEE + e)*HHH + head))*CCC + j] = o;
}

// ---------------- K3: ht_att -> bf16 out ----------------------------------
__global__ __launch_bounds__(256) void k_htatt(const float* __restrict__ eatt,
    const int* __restrict__ hts, unsigned short* __restrict__ htB) {
  int b = blockIdx.x; int doc = b >> 10; int r = b & 1023;
  int h0 = hts[(doc*PPP + r)*2 + 0];
  int t0 = hts[(doc*PPP + r)*2 + 1];
  const float* ea0 = &eatt[(size_t)((doc*EEE + h0)*HHH)*CCC];
  const float* ea1 = &eatt[(size_t)((doc*EEE + t0)*HHH)*CCC];
  int j = threadIdx.x * 4;
  float vx=0.f, vy=0.f, vz=0.f, vw=0.f;
#pragma unroll
  for (int hh = 0; hh < HHH; ++hh) {
    const float4 a  = *(const float4*)&ea0[hh*CCC + j];
    const float4 bq = *(const float4*)&ea1[hh*CCC + j];
    vx += a.x*bq.x; vy += a.y*bq.y; vz += a.z*bq.z; vw += a.w*bq.w;
  }
  const float inv12 = 1.f/12.f;
  vx *= inv12; vy *= inv12; vz *= inv12; vw *= inv12;
  float part = vx + vy + vz + vw;
  __shared__ float red[4];
  for (int off = 32; off > 0; off >>= 1) part += __shfl_down(part, off, 64);
  int lane = threadIdx.x & 63, wv = threadIdx.x >> 6;
  if (lane == 0) red[wv] = part;
  __syncthreads();
  if (threadIdx.x == 0) red[0] = red[0]+red[1]+red[2]+red[3];
  __syncthreads();
  float sc = 1.f / (red[0] + 1e-5f);
  unsigned short o[4];
  o[0] = f32_to_bf16u(vx*sc); o[1] = f32_to_bf16u(vy*sc);
  o[2] = f32_to_bf16u(vz*sc); o[3] = f32_to_bf16u(vw*sc);
  *(uint2*)&htB[((size_t)(doc*PPP + r))*CCC + j] = *(const uint2*)o;
}

// ---------------- K3b: pack Wh|Wt -> bf16 [2][768][1536] -------------------
__global__ __launch_bounds__(256) void k_packW(const float* __restrict__ Wh,
    const float* __restrict__ Wt, unsigned short* __restrict__ WB) {
  int gid = blockIdx.x*256 + threadIdx.x;
  int half = gid >= 147456;
  int loc = half ? gid - 147456 : gid;
  const float* src = (half ? Wt : Wh) + (size_t)loc*8;
  float4 v0 = *(const float4*)src;
  float4 v1 = *(const float4*)(src+4);
  unsigned short o[8];
  o[0]=f32_to_bf16u(v0.x); o[1]=f32_to_bf16u(v0.y); o[2]=f32_to_bf16u(v0.z); o[3]=f32_to_bf16u(v0.w);
  o[4]=f32_to_bf16u(v1.x); o[5]=f32_to_bf16u(v1.y); o[6]=f32_to_bf16u(v1.z); o[7]=f32_to_bf16u(v1.w);
  *(uint4*)&WB[(size_t)half*1179648 + (size_t)loc*8] = *(const uint4*)o;
}

// ---------------- K3c: seqT bf16 [doc][768][1024] (transpose) --------------
__global__ __launch_bounds__(256) void k_seqT(const float* __restrict__ seq,
    unsigned short* __restrict__ seqTB) {
  __shared__ float tl[64][65];
  int d0 = blockIdx.x * 64, c0 = blockIdx.y * 64, doc = blockIdx.z;
  int t = threadIdx.x;
#pragma unroll
  for (int rep = 0; rep < 4; ++rep) {
    int cr = rep*16 + (t >> 4);
    int d4 = (t & 15) * 4;
    float4 v = *(const float4*)&seq[((size_t)doc*CCC + c0 + cr)*DDD + d0 + d4];
    tl[cr][d4+0]=v.x; tl[cr][d4+1]=v.y; tl[cr][d4+2]=v.z; tl[cr][d4+3]=v.w;
  }
  __syncthreads();
#pragma unroll
  for (int rep = 0; rep < 4; ++rep) {
    int dr = rep*16 + (t >> 4);
    int c4 = (t & 15) * 4;
    unsigned short o[4];
#pragma unroll
    for (int kq = 0; kq < 4; ++kq)
      o[kq] = f32_to_bf16u(tl[c4+kq][dr]);
    *(uint2*)&seqTB[((size_t)doc*DDD + d0 + dr)*CCC + c0 + c4] = *(const uint2*)o;
  }
}

// ---------------- K4: rs = htatt @ seq  (bf16 MFMA, reg-staged LDS) --------
__global__ __launch_bounds__(256) void k_rs_mfma(
    const unsigned short* __restrict__ htB,    // [doc][1024][1024]
    const unsigned short* __restrict__ seqTB,  // [doc][768][1024]
    unsigned short* __restrict__ rsB) {        // [4096][768]
  __shared__ unsigned short A_l[4096];
  __shared__ unsigned short B_l[4096];
  const int n0 = blockIdx.x * 128;
  const int m0 = blockIdx.y * 128;
  const int doc = m0 >> 10;
  const int mloc = m0 & 1023;
  const int t = threadIdx.x;
  const int lane = t & 63;
  const int ln = lane & 15, q4 = lane >> 4;
  const int w = t >> 6;
  const int wr = w >> 1, wc = w & 1;

  const int r0 = t >> 2;
  const int koff = (t & 3) * 8;
  const unsigned short* srcA0 = htB + ((size_t)doc*CCC + mloc + r0)*CCC + koff;
  const unsigned short* srcA1 = htB + ((size_t)doc*CCC + mloc + r0 + 64)*CCC + koff;
  const unsigned short* srcB0 = seqTB + ((size_t)doc*DDD + n0 + r0)*CCC + koff;
  const unsigned short* srcB1 = seqTB + ((size_t)doc*DDD + n0 + r0 + 64)*CCC + koff;

  floatx4 acc[4][4];
#pragma unroll
  for (int i = 0; i < 4; ++i)
#pragma unroll
    for (int j = 0; j < 4; ++j) acc[i][j] = (floatx4){0.f,0.f,0.f,0.f};

  for (int k0 = 0; k0 < CCC; k0 += 32) {
    uint4 va0 = *(const uint4*)(srcA0 + k0);
    uint4 va1 = *(const uint4*)(srcA1 + k0);
    uint4 vb0 = *(const uint4*)(srcB0 + k0);
    uint4 vb1 = *(const uint4*)(srcB1 + k0);
    __syncthreads();
    *(uint4*)&A_l[(size_t)t*8]       = va0;
    *(uint4*)&A_l[(size_t)(t+256)*8] = va1;
    *(uint4*)&B_l[(size_t)t*8]       = vb0;
    *(uint4*)&B_l[(size_t)(t+256)*8] = vb1;
    __syncthreads();
    short8v a[4], b[4];
#pragma unroll
    for (int rt = 0; rt < 4; ++rt)
      a[rt] = *(const short8v*)&A_l[((wr*64 + rt*16 + ln)*4 + q4)*8];
#pragma unroll
    for (int nt = 0; nt < 4; ++nt)
      b[nt] = *(const short8v*)&B_l[((wc*64 + nt*16 + ln)*4 + q4)*8];
#pragma unroll
    for (int rt = 0; rt < 4; ++rt)
#pragma unroll
      for (int nt = 0; nt < 4; ++nt)
        acc[rt][nt] = __builtin_amdgcn_mfma_f32_16x16x32_bf16(a[rt], b[nt], acc[rt][nt], 0, 0, 0);
  }
#pragma unroll
  for (int rt = 0; rt < 4; ++rt)
#pragma unroll
    for (int nt = 0; nt < 4; ++nt) {
      int col = n0 + wc*64 + nt*16 + ln;
#pragma unroll
      for (int reg = 0; reg < 4; ++reg) {
        int row = m0 + wr*64 + rt*16 + q4*4 + reg;
        rsB[(size_t)row*DDD + col] = f32_to_bf16u(acc[rt][nt][reg]);
      }
    }
}

// ---------------- K5: heads GEMM (bf16 MFMA, gather-A, tanh epilogue) ------
__global__ __launch_bounds__(256) void k_heads_mfma(
    const unsigned short* __restrict__ eembB,  // [4*42][768]
    const unsigned short* __restrict__ rsB,    // [4096][768]
    const int* __restrict__ hts,
    const unsigned short* __restrict__ WB,     // [2][768][1536]
    const float* __restrict__ bh, const float* __restrict__ bt,
    float* __restrict__ hsb, float* __restrict__ tsb) {
  __shared__ unsigned short A_l[4096];
  __shared__ unsigned short B_l[4096];
  const int which = blockIdx.z;
  const int n0 = blockIdx.x * 128;
  const int m0 = blockIdx.y * 128;
  const int doc = m0 >> 10;
  const int t = threadIdx.x;
  const int lane = t & 63;
  const int ln = lane & 15, q4 = lane >> 4;
  const int w = t >> 6;
  const int wr = w >> 1, wc = w & 1;

  const int r0 = t >> 2;
  const int koff = (t & 3) * 8;
  const int rgA0 = m0 + r0, rgA1 = m0 + r0 + 64;
  const int idx0 = hts[rgA0*2 + which];
  const int idx1 = hts[rgA1*2 + which];
  const unsigned short* srcE0 = eembB + (size_t)(doc*EEE + idx0)*DDD + koff;
  const unsigned short* srcE1 = eembB + (size_t)(doc*EEE + idx1)*DDD + koff;
  const unsigned short* srcR0 = rsB + (size_t)rgA0*DDD + koff;
  const unsigned short* srcR1 = rsB + (size_t)rgA1*DDD + koff;
  const unsigned short* WBz = WB + (size_t)which*1179648;
  const unsigned short* srcW0 = WBz + (size_t)(n0 + r0)*1536 + koff;
  const unsigned short* srcW1 = WBz + (size_t)(n0 + r0 + 64)*1536 + koff;

  floatx4 acc[4][4];
#pragma unroll
  for (int i = 0; i < 4; ++i)
#pragma unroll
    for (int j = 0; j < 4; ++j) acc[i][j] = (floatx4){0.f,0.f,0.f,0.f};

  for (int k0 = 0; k0 < 1536; k0 += 32) {
    uint4 va0 = (k0 < DDD) ? *(const uint4*)(srcE0 + k0) : *(const uint4*)(srcR0 + (k0 - DDD));
    uint4 va1 = (k0 < DDD) ? *(const uint4*)(srcE1 + k0) : *(const uint4*)(srcR1 + (k0 - DDD));
    uint4 vb0 = *(const uint4*)(srcW0 + k0);
    uint4 vb1 = *(const uint4*)(srcW1 + k0);
    __syncthreads();
    *(uint4*)&A_l[(size_t)t*8]       = va0;
    *(uint4*)&A_l[(size_t)(t+256)*8] = va1;
    *(uint4*)&B_l[(size_t)t*8]       = vb0;
    *(uint4*)&B_l[(size_t)(t+256)*8] = vb1;
    __syncthreads();
    short8v a[4], b[4];
#pragma unroll
    for (int rt = 0; rt < 4; ++rt)
      a[rt] = *(const short8v*)&A_l[((wr*64 + rt*16 + ln)*4 + q4)*8];
#pragma unroll
    for (int nt = 0; nt < 4; ++nt)
      b[nt] = *(const short8v*)&B_l[((wc*64 + nt*16 + ln)*4 + q4)*8];
#pragma unroll
    for (int rt = 0; rt < 4; ++rt)
#pragma unroll
      for (int nt = 0; nt < 4; ++nt)
        acc[rt][nt] = __builtin_amdgcn_mfma_f32_16x16x32_bf16(a[rt], b[nt], acc[rt][nt], 0, 0, 0);
  }
  const float* bias = which ? bt : bh;
  float* outp = which ? tsb : hsb;
#pragma unroll
  for (int rt = 0; rt < 4; ++rt)
#pragma unroll
    for (int nt = 0; nt < 4; ++nt) {
      int col = n0 + wc*64 + nt*16 + ln;
      float bsv = bias[col];
#pragma unroll
      for (int reg = 0; reg < 4; ++reg) {
        int row = m0 + wr*64 + rt*16 + q4*4 + reg;
        outp[(size_t)row*DDD + col] = tanhf(acc[rt][nt][reg] + bsv);
      }
    }
}

// ------- K6a: pack Wb fp32 -> fp16, fragment-major global layout -----------
// element (ki, n, j): js=j>>5, q=(j>>3)&3, e=j&7, nt=n>>4, lnn=n&15
// chunk c = ((js*7+nt)*4+q)*16 + lnn ; Wp[ki*7168 + c*8 + e]
__global__ __launch_bounds__(256) void k_prep_w(const float* __restrict__ Wb,
    unsigned short* __restrict__ Wp) {
  int t = blockIdx.x*256 + threadIdx.x;
  int j8 = (t & 7) * 8;
  int n = (t >> 3) % NPAD;
  int ki = t / 896;
  unsigned short o[8];
  if (n < NK) {
    const float* src = &Wb[(size_t)n*49152 + ki*64 + j8];
    float4 v0 = *(const float4*)src;
    float4 v1 = *(const float4*)(src+4);
    o[0]=f32_to_f16u(v0.x); o[1]=f32_to_f16u(v0.y); o[2]=f32_to_f16u(v0.z); o[3]=f32_to_f16u(v0.w);
    o[4]=f32_to_f16u(v1.x); o[5]=f32_to_f16u(v1.y); o[6]=f32_to_f16u(v1.z); o[7]=f32_to_f16u(v1.w);
  } else {
#pragma unroll
    for (int e=0;e<8;++e) o[e]=0;
  }
  int js = (t & 7) >> 2, q = t & 3;
  int nt = n >> 4, lnn = n & 15;
  int c = ((js*7 + nt)*4 + q)*16 + lnn;
  *(uint4*)&Wp[(size_t)ki*7168 + c*8] = *(const uint4*)o;
}

// ------- K6b: hsT_g[i][r] = fp16(hs[r][i]) ---------------------------------
__global__ __launch_bounds__(256) void k_pack_hs(const float* __restrict__ hs,
    unsigned short* __restrict__ hsT) {
  __shared__ float tl[64][65];
  int i0 = blockIdx.x * 64, r0 = blockIdx.y * 64;
  int t = threadIdx.x;
#pragma unroll
  for (int rep = 0; rep < 4; ++rep) {
    int r = rep*16 + (t >> 4);
    int c4 = (t & 15) * 4;
    float4 v = *(const float4*)&hs[(size_t)(r0 + r)*DDD + i0 + c4];
    tl[r][c4+0]=v.x; tl[r][c4+1]=v.y; tl[r][c4+2]=v.z; tl[r][c4+3]=v.w;
  }
  __syncthreads();
#pragma unroll
  for (int rep = 0; rep < 4; ++rep) {
    int i = rep*16 + (t >> 4);
    int r4 = (t & 15) * 4;
    unsigned short o[4];
#pragma unroll
    for (int kq = 0; kq < 4; ++kq)
      o[kq] = f32_to_f16u(tl[r4+kq][i]);
    *(uint2*)&hsT[(size_t)(i0 + i)*4096 + r0 + r4] = *(const uint2*)o;
  }
}

// ------- K6: logits partials, fp16 MFMA, barrier-free K-loop ---------------
// grid (48, 32), 128 thr (2 waves, each wave = 64 rows, rt=4). 16 ki/slice.
// B-fragments read DIRECTLY from global Wp (fragment-major -> one coalesced
// dwordx4 per fragment, L1/L2-resident). No LDS for W, no barriers in loop.
__global__ __launch_bounds__(128) void k_logits_mfma(
    const unsigned short* __restrict__ hsT,   // [768][4096] fp16
    const float* __restrict__ tsb,            // [4096][768] fp32
    const unsigned short* __restrict__ Wp,    // [768 ki][896 c][8] fp16
    unsigned short* __restrict__ P) {         // [48][4096][112] fp16
  __shared__ unsigned short hsT_l[16*128];    // [ii][r] 4 KB
  const int slice = blockIdx.x;
  const int kbase = slice * 16;
  const int nb = slice >> 2;
  const int mtile = blockIdx.y;
  const int t = threadIdx.x;
  const int w = t >> 6;           // wave 0/1, owns rows w*64..w*64+63
  const int lane = t & 63;
  const int ln = lane & 15;
  const int q = lane >> 4;
  const int m0w = mtile*128 + w*64;

  // ---- stage hsT tile [16 ki][128 r] (256 x 16B chunks, 2 per thread) ----
#pragma unroll
  for (int rep = 0; rep < 2; ++rep) {
    int c16 = t + rep*128;
    int ii = c16 >> 4;
    int c8 = (c16 & 15) * 8;
    uint4 v = *(const uint4*)&hsT[(size_t)(kbase + ii)*4096 + mtile*128 + c8];
    *(uint4*)&hsT_l[ii*128 + c8] = v;
  }

  // ---- ts fragment rows -> fp16 pairs in registers ----
  __half2 tsr2[4][2][4];
#pragma unroll
  for (int rt = 0; rt < 4; ++rt) {
    int row = m0w + rt*16 + ln;
#pragma unroll
    for (int js = 0; js < 2; ++js) {
      const float* p = &tsb[(size_t)row*DDD + nb*64 + js*32 + q*8];
      float4 v0 = *(const float4*)p;
      float4 v1 = *(const float4*)(p+4);
      tsr2[rt][js][0] = __floats2half2_rn(v0.x, v0.y);
      tsr2[rt][js][1] = __floats2half2_rn(v0.z, v0.w);
      tsr2[rt][js][2] = __floats2half2_rn(v1.x, v1.y);
      tsr2[rt][js][3] = __floats2half2_rn(v1.z, v1.w);
    }
  }

  floatx4 acc[4][7];
#pragma unroll
  for (int rt = 0; rt < 4; ++rt)
#pragma unroll
    for (int nt = 0; nt < 7; ++nt)
      acc[rt][nt] = (floatx4){0.f,0.f,0.f,0.f};

  __syncthreads();   // hsT_l staged (only barrier in the kernel)

  const unsigned short* wb = Wp + (size_t)kbase*7168;
  for (int ii = 0; ii < 16; ++ii) {
    __half2 hh[4];
#pragma unroll
    for (int rt = 0; rt < 4; ++rt) {
      unsigned short hb = hsT_l[ii*128 + w*64 + rt*16 + ln];
      hh[rt] = __half2half2(__ushort_as_half(hb));
    }
#pragma unroll
    for (int js = 0; js < 2; ++js) {
      // 7 independent coalesced B-fragment loads (lane-linear in Wp)
      half8 b[7];
#pragma unroll
      for (int nt = 0; nt < 7; ++nt)
        b[nt] = __builtin_bit_cast(half8,
            *(const uint4*)&wb[((size_t)(js*7 + nt)*64 + lane)*8]);
      half8 a[4];
#pragma unroll
      for (int rt = 0; rt < 4; ++rt) {
        uint4 au;
        au.x = __builtin_bit_cast(unsigned int, __hmul2(hh[rt], tsr2[rt][js][0]));
        au.y = __builtin_bit_cast(unsigned int, __hmul2(hh[rt], tsr2[rt][js][1]));
        au.z = __builtin_bit_cast(unsigned int, __hmul2(hh[rt], tsr2[rt][js][2]));
        au.w = __builtin_bit_cast(unsigned int, __hmul2(hh[rt], tsr2[rt][js][3]));
        a[rt] = __builtin_bit_cast(half8, au);
      }
#pragma unroll
      for (int nt = 0; nt < 7; ++nt)
#pragma unroll
        for (int rt = 0; rt < 4; ++rt)
          acc[rt][nt] = __builtin_amdgcn_mfma_f32_16x16x32_f16(a[rt], b[nt], acc[rt][nt], 0, 0, 0);
    }
    wb += 7168;
  }

  // ---- epilogue: regular fp16 stores of this slice's partials ----
  unsigned short* Ps = P + (size_t)slice*(4096*NPAD);
#pragma unroll
  for (int nt = 0; nt < 7; ++nt) {
    int col = nt*16 + ln;
#pragma unroll
    for (int rt = 0; rt < 4; ++rt) {
#pragma unroll
      for (int reg = 0; reg < 4; ++reg) {
        int row = m0w + rt*16 + q*4 + reg;
        Ps[(size_t)row*NPAD + col] = f32_to_f16u(acc[rt][nt][reg]);
      }
    }
  }
}

// ------- K7: reduce 48 fp16 partial slices -> logits fp32 ------------------
__global__ __launch_bounds__(256) void k_logred(const unsigned short* __restrict__ P,
    float* __restrict__ out) {
  int idx = blockIdx.x*256 + threadIdx.x;    // 0 .. 4096*112-1
  int r = idx / NPAD;
  int c = idx % NPAD;
  if (c >= NK) return;
  float s = 0.f;
#pragma unroll
  for (int sl = 0; sl < NSLICE; ++sl)
    s += __half2float(__ushort_as_half(P[(size_t)sl*(4096*NPAD) + idx]));
  out[(size_t)r*NK + c] = s;
}

extern "C" void kernel_launch(void* const* d_in, const int* in_sizes, int n_in,
                              void* d_out, int out_size, void* d_ws, size_t ws_size,
                              hipStream_t stream) {
  const float* seq  = (const float*)d_in[0];
  const float* att  = (const float*)d_in[1];
  const float* Wh   = (const float*)d_in[2];
  const float* bh   = (const float*)d_in[3];
  const float* Wt   = (const float*)d_in[4];
  const float* bt   = (const float*)d_in[5];
  const float* Wb   = (const float*)d_in[6];
  const int* pos    = (const int*)d_in[7];
  const int* mask   = (const int*)d_in[8];
  const int* hts    = (const int*)d_in[9];
  float* out = (float*)d_out;

  float* ws = (float*)d_ws;
  // base layout (float slots): 14,842,880 f = 59.4 MB
  float*          eatt  = ws;                                   // 2,064,384 f
  unsigned short* htB   = (unsigned short*)(ws + 2064384);      // 4,194,304 us
  unsigned short* eembB = (unsigned short*)(ws + 4161536);      //   129,024 us
  unsigned short* seqTB = (unsigned short*)(ws + 4226048);      // 3,145,728 us
  unsigned short* WhtB  = (unsigned short*)(ws + 5798912);      // 2,359,296 us
  unsigned short* rsB   = (unsigned short*)(ws + 6978560);      // 3,145,728 us
  float*          hsb   = ws + 8551424;                         // 3,145,728 f
  float*          tsb   = ws + 11697152;                        // 3,145,728 f
  // aliases (valid by launch order):
  unsigned short* WpB   = (unsigned short*)eatt;   // 5,505,024 us; written after k_rs_mfma
  unsigned short* hsTB  = (unsigned short*)seqTB;  // 3,145,728 us; written after k_rs_mfma
  // P partials: [48][4096][112] fp16 = 22,020,096 us = 44 MB, placed after tsb
  // (d_ws is ~768 MB per harness poison fill; total used = 103 MB)
  unsigned short* Pp    = (unsigned short*)(ws + 14842880);

  k_eemb<<<dim3(EEE, NDOC), 256, 0, stream>>>(seq, pos, mask, eembB);
  k_eatt<<<dim3(HHH, EEE, NDOC), 256, 0, stream>>>(att, pos, mask, eatt);
  k_htatt<<<dim3(NDOC*PPP), 256, 0, stream>>>(eatt, hts, htB);
  k_packW<<<dim3(1152), 256, 0, stream>>>(Wh, Wt, WhtB);
  k_seqT<<<dim3(DDD/64, CCC/64, NDOC), 256, 0, stream>>>(seq, seqTB);
  k_rs_mfma<<<dim3(6, 32), 256, 0, stream>>>(htB, seqTB, rsB);
  k_prep_w<<<dim3(2688), 256, 0, stream>>>(Wb, WpB);
  k_heads_mfma<<<dim3(6, 32, 2), 256, 0, stream>>>(eembB, rsB, hts, WhtB, bh, bt, hsb, tsb);
  k_pack_hs<<<dim3(DDD/64, 4096/64), 256, 0, stream>>>(hsb, hsTB);
  k_logits_mfma<<<dim3(NSLICE, 32), 128, 0, stream>>>(hsTB, tsb, WpB, Pp);
  k_logred<<<dim3(4096*NPAD/256), 256, 0, stream>>>(Pp, out);
}